// Round 1
// baseline (7495.016 us; speedup 1.0000x reference)
//
#include <hip/hip_runtime.h>
#include <math.h>

typedef _Float16 f16;
using f16x8 = __attribute__((ext_vector_type(8))) _Float16;
using f32x4 = __attribute__((ext_vector_type(4))) float;

// Problem sizes (fixed)
#define NB 64
#define NS 1024
#define NDIM 512
#define NH 512

// ws layout (bytes): xsB | w16 (Wi_f,Wh_f,Wi_b,Wh_b f16) | flags
#define XSB_OFF   0ULL
#define W16_OFF   134217728ULL
#define FLAG_OFF  136314880ULL   // W16_OFF + 4*512*512*2
#define FLAG_BYTES 131072        // 8 dg * 1024 steps * 4 slices * 4B

// ---------------- weight conversion fp32 -> fp16 ----------------
__global__ __launch_bounds__(256) void cvt_w(const float* __restrict__ wi_f,
                                             const float* __restrict__ wh_f,
                                             const float* __restrict__ wi_b,
                                             const float* __restrict__ wh_b,
                                             f16* __restrict__ o) {
    int i = blockIdx.x * 256 + threadIdx.x;
    if (i < 512 * 512) {
        o[i]              = (f16)wi_f[i];
        o[262144 + i]     = (f16)wh_f[i];
        o[2 * 262144 + i] = (f16)wi_b[i];
        o[3 * 262144 + i] = (f16)wh_b[i];
    }
}

// ---------------- input projection GEMM ----------------
// xs[dir] = x @ Wi^T + bi.  M=65536, N=512, K=512. 128x128 tile, BK=32, 4 waves.
#define PLDA 40  // padded row (f16 elems): 32 + 8 -> 80B row stride (bank-friendly)

__global__ __launch_bounds__(256)
void proj(const float* __restrict__ x, const f16* __restrict__ w16base,
          const float* __restrict__ bi_f, const float* __restrict__ bi_b,
          float* __restrict__ xsF, float* __restrict__ xsB)
{
    __shared__ f16 Ah[128 * PLDA];
    __shared__ f16 Bh[128 * PLDA];

    int bidx = blockIdx.x;
    int dir = bidx >> 11;
    int rem = bidx & 2047;
    int mt = rem >> 2, nt = rem & 3;

    const f16* Wi16 = w16base + (dir ? 2 * 262144 : 0);
    const float* bi = dir ? bi_b : bi_f;
    float* xs = dir ? xsB : xsF;

    int tid = threadIdx.x;
    int lane = tid & 63, w = tid >> 6;
    int wm = (w >> 1) * 64, wn = (w & 1) * 64;

    f32x4 acc[4][4] = {};

    for (int ks = 0; ks < 16; ++ks) {
        int k0 = ks * 32;
        // stage A: x fp32 -> f16, 128 rows x 32 k
        for (int it = 0; it < 4; ++it) {
            int idx = tid + it * 256;          // 0..1023
            int row = idx >> 3, slot = idx & 7;
            float4 v = *(const float4*)(x + (size_t)(mt * 128 + row) * 512 + k0 + slot * 4);
            f16* dst = Ah + row * PLDA + slot * 4;
            dst[0] = (f16)v.x; dst[1] = (f16)v.y; dst[2] = (f16)v.z; dst[3] = (f16)v.w;
        }
        // stage B: Wi16 rows (output dims j), 128 rows x 32 k
        for (int it = 0; it < 2; ++it) {
            int idx = tid + it * 256;          // 0..511
            int row = idx >> 2, slot = idx & 3;
            uint4 v = *(const uint4*)(Wi16 + (size_t)(nt * 128 + row) * 512 + k0 + slot * 8);
            *(uint4*)(Bh + row * PLDA + slot * 8) = v;
        }
        __syncthreads();

        f16x8 af[4], bf[4];
        for (int i = 0; i < 4; ++i) {
            int arow = wm + i * 16 + (lane & 15);
            af[i] = *(const f16x8*)(Ah + arow * PLDA + ((lane >> 4) * 8));
            int brow = wn + i * 16 + (lane & 15);
            bf[i] = *(const f16x8*)(Bh + brow * PLDA + ((lane >> 4) * 8));
        }
        for (int i = 0; i < 4; ++i)
            for (int j = 0; j < 4; ++j)
                acc[i][j] = __builtin_amdgcn_mfma_f32_16x16x32_f16(af[i], bf[j], acc[i][j], 0, 0, 0);
        __syncthreads();
    }

    // epilogue: C layout col=lane&15, row=(lane>>4)*4+reg
    for (int i = 0; i < 4; ++i) {
        for (int j = 0; j < 4; ++j) {
            int jg = nt * 128 + wn + j * 16 + (lane & 15);
            float bv = bi[jg];
            for (int r = 0; r < 4; ++r) {
                int mg = mt * 128 + wm + i * 16 + (lane >> 4) * 4 + r;
                xs[(size_t)mg * 512 + jg] = acc[i][j][r] + bv;
            }
        }
    }
}

// ---------------- recurrence ----------------
// 32 WGs: dir(2) x group(4 batches-of-16) x slice(4 j-chunks-of-128).
// Wh slice resident in LDS (f16, padded rows). h exchanged via xs buffer
// (overwritten in place with packed f16 hi/lo), per-step release/acquire flags.
#define WH_LDA 520   // 512 + 8 f16 -> 1040B row stride
#define HS_LDA 264   // 256 + 8 f16 -> 528B row stride

__global__ __launch_bounds__(256)
void rnn_rec(const float* __restrict__ h0, const f16* __restrict__ w16base,
             const float* __restrict__ bh_f, const float* __restrict__ bh_b,
             float* xsF, float* xsB, unsigned* flags)
{
    extern __shared__ char smem[];
    f16* wh  = (f16*)smem;                          // 128 x WH_LDA
    f16* hhi = (f16*)(smem + 128 * WH_LDA * 2);     // 16 x HS_LDA
    f16* hlo = hhi + 16 * HS_LDA;                   // 16 x HS_LDA

    int bid = blockIdx.x;              // p = slice*8 + (dir*4+g): group co-located per XCD (heuristic)
    int dg = bid & 7, slice = bid >> 3;
    int dir = dg >> 2, g = dg & 3;

    float* xs = dir ? xsB : xsF;
    const f16* Wh16 = w16base + 262144 + (dir ? 2 * 262144 : 0);
    const float* bh = dir ? bh_b : bh_f;
    int b0 = g * 16;
    int tid = threadIdx.x, lane = tid & 63, w = tid >> 6;

    // load Wh slice rows [slice*128, +128) into LDS
    for (int it = 0; it < 32; ++it) {
        int idx = tid + it * 256;      // 128 rows x 64 16B-slots
        int row = idx >> 6, slot = idx & 63;
        uint4 v = *(const uint4*)(Wh16 + (size_t)(slice * 128 + row) * 512 + slot * 8);
        *(uint4*)(wh + row * WH_LDA + slot * 8) = v;
    }

    int jl0 = w * 32 + (lane & 15);    // local j for acc0; acc1 is +16
    int jg0 = slice * 128 + jl0;
    int jg1 = jg0 + 16;
    float bh0 = bh[jg0], bh1 = bh[jg1];

    __syncthreads();

    unsigned* gflags = flags + (size_t)dg * 1024 * 4;
    unsigned* xsu = (unsigned*)xs;

    for (int st = 0; st < 1024; ++st) {
        int tt = dir ? 1023 - st : st;
        int ttp = dir ? tt + 1 : tt - 1;

        if (st > 0 && tid < 4) {
            unsigned* f = gflags + (size_t)(st - 1) * 4 + tid;
            while (__hip_atomic_load(f, __ATOMIC_ACQUIRE, __HIP_MEMORY_SCOPE_AGENT) == 0u)
                __builtin_amdgcn_s_sleep(1);
        }
        __syncthreads();   // flags acquired; also guards LDS h-plane reuse

        f32x4 acc0 = {0.f, 0.f, 0.f, 0.f}, acc1 = {0.f, 0.f, 0.f, 0.f};

        for (int kh = 0; kh < 2; ++kh) {
            // stage h_{t-1}[16 x 256] as hi/lo f16 planes
            for (int it = 0; it < 4; ++it) {
                int idx = tid + it * 256;         // 16 rows x 64 uint4
                int row = idx >> 6, col = idx & 63;
                f16 hi4[4], lo4[4];
                if (st == 0) {
                    float4 v = *(const float4*)(h0 + (size_t)(b0 + row) * 512 + kh * 256 + col * 4);
                    float vv[4] = {v.x, v.y, v.z, v.w};
                    for (int q = 0; q < 4; ++q) {
                        f16 h_ = (f16)vv[q];
                        hi4[q] = h_;
                        lo4[q] = (f16)(vv[q] - (float)h_);
                    }
                } else {
                    uint4 v = *(const uint4*)(xsu + ((size_t)(b0 + row) * 1024 + ttp) * 512 + kh * 256 + col * 4);
                    unsigned uu[4] = {v.x, v.y, v.z, v.w};
                    for (int q = 0; q < 4; ++q) {
                        unsigned short hb = (unsigned short)(uu[q] & 0xffffu);
                        unsigned short lb = (unsigned short)(uu[q] >> 16);
                        hi4[q] = __builtin_bit_cast(f16, hb);
                        lo4[q] = __builtin_bit_cast(f16, lb);
                    }
                }
                f16* dh = hhi + row * HS_LDA + col * 4;
                f16* dl = hlo + row * HS_LDA + col * 4;
                for (int q = 0; q < 4; ++q) { dh[q] = hi4[q]; dl[q] = lo4[q]; }
            }
            __syncthreads();

            for (int kc = 0; kc < 8; ++kc) {
                int klocal = kc * 32 + ((lane >> 4) * 8);
                f16x8 ahi = *(const f16x8*)(hhi + (lane & 15) * HS_LDA + klocal);
                f16x8 alo = *(const f16x8*)(hlo + (lane & 15) * HS_LDA + klocal);
                int kglob = kh * 256 + klocal;
                f16x8 bf0 = *(const f16x8*)(wh + (size_t)jl0 * WH_LDA + kglob);
                f16x8 bf1 = *(const f16x8*)(wh + (size_t)(jl0 + 16) * WH_LDA + kglob);
                acc0 = __builtin_amdgcn_mfma_f32_16x16x32_f16(ahi, bf0, acc0, 0, 0, 0);
                acc0 = __builtin_amdgcn_mfma_f32_16x16x32_f16(alo, bf0, acc0, 0, 0, 0);
                acc1 = __builtin_amdgcn_mfma_f32_16x16x32_f16(ahi, bf1, acc1, 0, 0, 0);
                acc1 = __builtin_amdgcn_mfma_f32_16x16x32_f16(alo, bf1, acc1, 0, 0, 0);
            }
            __syncthreads();
        }

        // epilogue: y = Wh.h + xs + bh ; h = tanh(y) ; overwrite xs with packed hi/lo
        for (int r = 0; r < 4; ++r) {
            int bl = (lane >> 4) * 4 + r;
            size_t base = ((size_t)(b0 + bl) * 1024 + tt) * 512;
            {
                float y = acc0[r] + xs[base + jg0] + bh0;
                float h = tanhf(y);
                f16 hi = (f16)h;
                f16 lo = (f16)(h - (float)hi);
                unsigned word = ((unsigned)__builtin_bit_cast(unsigned short, lo) << 16) |
                                (unsigned)__builtin_bit_cast(unsigned short, hi);
                xsu[base + jg0] = word;
            }
            {
                float y = acc1[r] + xs[base + jg1] + bh1;
                float h = tanhf(y);
                f16 hi = (f16)h;
                f16 lo = (f16)(h - (float)hi);
                unsigned word = ((unsigned)__builtin_bit_cast(unsigned short, lo) << 16) |
                                (unsigned)__builtin_bit_cast(unsigned short, hi);
                xsu[base + jg1] = word;
            }
        }
        __syncthreads();
        if (tid == 0) {
            __threadfence();
            __hip_atomic_store(gflags + (size_t)st * 4 + slice, 1u,
                               __ATOMIC_RELEASE, __HIP_MEMORY_SCOPE_AGENT);
        }
    }
}

// ---------------- merge: out = h_f + h_b (both stored packed hi/lo) ----------------
__device__ inline float unpack_sum(unsigned u) {
    unsigned short hb = (unsigned short)(u & 0xffffu);
    unsigned short lb = (unsigned short)(u >> 16);
    return (float)__builtin_bit_cast(f16, hb) + (float)__builtin_bit_cast(f16, lb);
}

__global__ __launch_bounds__(256)
void merge_out(const unsigned* xsF, const unsigned* xsB, float* out)
{
    size_t i = ((size_t)blockIdx.x * 256 + threadIdx.x) * 4;
    size_t stride = (size_t)gridDim.x * 1024;
    for (; i < 33554432ULL; i += stride) {
        uint4 a = *(const uint4*)(xsF + i);
        uint4 b = *(const uint4*)(xsB + i);
        float4 o;
        o.x = unpack_sum(a.x) + unpack_sum(b.x);
        o.y = unpack_sum(a.y) + unpack_sum(b.y);
        o.z = unpack_sum(a.z) + unpack_sum(b.z);
        o.w = unpack_sum(a.w) + unpack_sum(b.w);
        *(float4*)(out + i) = o;
    }
}

__global__ __launch_bounds__(256)
void copy_hidden(const float* __restrict__ hs, float* __restrict__ out)
{
    size_t i = (size_t)blockIdx.x * 256 + threadIdx.x;
    if (i < 32768) out[33554432ULL + i] = hs[i];
}

// ---------------- launch ----------------
extern "C" void kernel_launch(void* const* d_in, const int* in_sizes, int n_in,
                              void* d_out, int out_size, void* d_ws, size_t ws_size,
                              hipStream_t stream) {
    const float* x    = (const float*)d_in[0];
    const float* hs   = (const float*)d_in[1];
    const float* Wi_f = (const float*)d_in[2];
    const float* bi_f = (const float*)d_in[3];
    const float* Wh_f = (const float*)d_in[4];
    const float* bh_f = (const float*)d_in[5];
    const float* Wi_b = (const float*)d_in[6];
    const float* bi_b = (const float*)d_in[7];
    const float* Wh_b = (const float*)d_in[8];
    const float* bh_b = (const float*)d_in[9];

    float* out = (float*)d_out;
    char* ws = (char*)d_ws;

    float* xsF = out;                           // forward history lives in d_out
    float* xsB = (float*)(ws + XSB_OFF);
    f16* w16   = (f16*)(ws + W16_OFF);
    unsigned* flags = (unsigned*)(ws + FLAG_OFF);

    hipMemsetAsync(flags, 0, FLAG_BYTES, stream);
    cvt_w<<<1024, 256, 0, stream>>>(Wi_f, Wh_f, Wi_b, Wh_b, w16);
    proj<<<4096, 256, 0, stream>>>(x, w16, bi_f, bi_b, xsF, xsB);

    (void)hipFuncSetAttribute((const void*)rnn_rec,
                              hipFuncAttributeMaxDynamicSharedMemorySize, 150016);
    rnn_rec<<<32, 256, 150016, stream>>>(hs, w16, bh_f, bh_b, xsF, xsB, flags);

    merge_out<<<2048, 256, 0, stream>>>((const unsigned*)xsF, (const unsigned*)xsB, out);
    copy_hidden<<<128, 256, 0, stream>>>(hs, out);
}

// Round 2
// 4004.165 us; speedup vs baseline: 1.8718x; 1.8718x over previous
//
#include <hip/hip_runtime.h>
#include <math.h>

typedef _Float16 f16;
using f16x8 = __attribute__((ext_vector_type(8))) _Float16;
using f32x4 = __attribute__((ext_vector_type(4))) float;
using u32x4 = __attribute__((ext_vector_type(4))) unsigned;
using u32x2 = __attribute__((ext_vector_type(2))) unsigned;

// Problem sizes (fixed)
#define NB 64
#define NS 1024
#define NDIM 512
#define NH 512

// ws layout (bytes): xsB | w16 (Wi_f,Wh_f,Wi_b,Wh_b f16) | flags
#define XSB_OFF   0ULL
#define W16_OFF   134217728ULL
#define FLAG_OFF  136314880ULL   // W16_OFF + 4*512*512*2
#define FLAG_BYTES 131072        // 8 dg * 1024 steps * 4 slices * 4B

// ---------------- device-coherent (L2-bypass) memory helpers ----------------
// All cross-WG data moves with sc0 sc1 ops: write-through to / read from the
// shared L3 coherence point. No buffer_wbl2 / buffer_inv anywhere.

__device__ inline unsigned ld_cg_u32(const unsigned* p) {
    unsigned r;
    asm volatile("global_load_dword %0, %1, off sc0 sc1\n\t"
                 "s_waitcnt vmcnt(0)"
                 : "=v"(r) : "v"(p) : "memory");
    return r;
}

__device__ inline void st_cg_u32(unsigned* p, unsigned v) {
    asm volatile("global_store_dword %0, %1, off sc0 sc1"
                 :: "v"(p), "v"(v) : "memory");
}

// 8 x dwordx4 issued together; waits only the first 4 (vmcnt(4)).
__device__ inline void ld_cg_8x4(const unsigned* p0, const unsigned* p1,
                                 const unsigned* p2, const unsigned* p3,
                                 const unsigned* p4, const unsigned* p5,
                                 const unsigned* p6, const unsigned* p7,
                                 u32x4& r0, u32x4& r1, u32x4& r2, u32x4& r3,
                                 u32x4& r4, u32x4& r5, u32x4& r6, u32x4& r7) {
    asm volatile(
        "global_load_dwordx4 %0, %8, off sc0 sc1\n\t"
        "global_load_dwordx4 %1, %9, off sc0 sc1\n\t"
        "global_load_dwordx4 %2, %10, off sc0 sc1\n\t"
        "global_load_dwordx4 %3, %11, off sc0 sc1\n\t"
        "global_load_dwordx4 %4, %12, off sc0 sc1\n\t"
        "global_load_dwordx4 %5, %13, off sc0 sc1\n\t"
        "global_load_dwordx4 %6, %14, off sc0 sc1\n\t"
        "global_load_dwordx4 %7, %15, off sc0 sc1\n\t"
        "s_waitcnt vmcnt(4)"
        : "=&v"(r0), "=&v"(r1), "=&v"(r2), "=&v"(r3),
          "=&v"(r4), "=&v"(r5), "=&v"(r6), "=&v"(r7)
        : "v"(p0), "v"(p1), "v"(p2), "v"(p3),
          "v"(p4), "v"(p5), "v"(p6), "v"(p7)
        : "memory");
    __builtin_amdgcn_sched_barrier(0);
}

__device__ inline void ld_cg_2x4(const unsigned* pa, const unsigned* pb,
                                 u32x4& a, u32x4& b) {
    asm volatile(
        "global_load_dwordx4 %0, %2, off sc0 sc1\n\t"
        "global_load_dwordx4 %1, %3, off sc0 sc1\n\t"
        "s_waitcnt vmcnt(0)"
        : "=&v"(a), "=&v"(b)
        : "v"(pa), "v"(pb)
        : "memory");
    __builtin_amdgcn_sched_barrier(0);
}

#define WAIT_LGKM0 do { asm volatile("s_waitcnt lgkmcnt(0)" ::: "memory"); \
                        __builtin_amdgcn_sched_barrier(0); } while (0)
#define WAIT_VM0   do { asm volatile("s_waitcnt vmcnt(0)"   ::: "memory"); \
                        __builtin_amdgcn_sched_barrier(0); } while (0)
#define RAW_BAR    do { __builtin_amdgcn_s_barrier(); \
                        __builtin_amdgcn_sched_barrier(0); } while (0)

__device__ inline float fast_tanh(float y) {
    // tanh(y) = 1 - 2/(exp2(2*log2e*y)+1); exact at both saturating tails.
    float t = __builtin_amdgcn_exp2f(y * 2.8853900817779268f);
    return 1.0f - 2.0f * __builtin_amdgcn_rcpf(t + 1.0f);
}

__device__ inline unsigned pack_hilo(float h) {
    f16 hi = (f16)h;
    f16 lo = (f16)(h - (float)hi);
    return ((unsigned)__builtin_bit_cast(unsigned short, lo) << 16) |
           (unsigned)__builtin_bit_cast(unsigned short, hi);
}

// ---------------- weight conversion fp32 -> fp16 ----------------
__global__ __launch_bounds__(256) void cvt_w(const float* __restrict__ wi_f,
                                             const float* __restrict__ wh_f,
                                             const float* __restrict__ wi_b,
                                             const float* __restrict__ wh_b,
                                             f16* __restrict__ o) {
    int i = blockIdx.x * 256 + threadIdx.x;
    if (i < 512 * 512) {
        o[i]              = (f16)wi_f[i];
        o[262144 + i]     = (f16)wh_f[i];
        o[2 * 262144 + i] = (f16)wi_b[i];
        o[3 * 262144 + i] = (f16)wh_b[i];
    }
}

// ---------------- input projection GEMM ----------------
// xs[dir] = x @ Wi^T + bi.  M=65536, N=512, K=512. 128x128 tile, BK=32, 4 waves.
#define PLDA 40  // padded row (f16 elems)

__global__ __launch_bounds__(256)
void proj(const float* __restrict__ x, const f16* __restrict__ w16base,
          const float* __restrict__ bi_f, const float* __restrict__ bi_b,
          float* __restrict__ xsF, float* __restrict__ xsB)
{
    __shared__ f16 Ah[128 * PLDA];
    __shared__ f16 Bh[128 * PLDA];

    int bidx = blockIdx.x;
    int dir = bidx >> 11;
    int rem = bidx & 2047;
    int mt = rem >> 2, nt = rem & 3;

    const f16* Wi16 = w16base + (dir ? 2 * 262144 : 0);
    const float* bi = dir ? bi_b : bi_f;
    float* xs = dir ? xsB : xsF;

    int tid = threadIdx.x;
    int lane = tid & 63, w = tid >> 6;
    int wm = (w >> 1) * 64, wn = (w & 1) * 64;

    f32x4 acc[4][4] = {};

    for (int ks = 0; ks < 16; ++ks) {
        int k0 = ks * 32;
        for (int it = 0; it < 4; ++it) {
            int idx = tid + it * 256;
            int row = idx >> 3, slot = idx & 7;
            float4 v = *(const float4*)(x + (size_t)(mt * 128 + row) * 512 + k0 + slot * 4);
            f16* dst = Ah + row * PLDA + slot * 4;
            dst[0] = (f16)v.x; dst[1] = (f16)v.y; dst[2] = (f16)v.z; dst[3] = (f16)v.w;
        }
        for (int it = 0; it < 2; ++it) {
            int idx = tid + it * 256;
            int row = idx >> 2, slot = idx & 3;
            uint4 v = *(const uint4*)(Wi16 + (size_t)(nt * 128 + row) * 512 + k0 + slot * 8);
            *(uint4*)(Bh + row * PLDA + slot * 8) = v;
        }
        __syncthreads();

        f16x8 af[4], bf[4];
        for (int i = 0; i < 4; ++i) {
            int arow = wm + i * 16 + (lane & 15);
            af[i] = *(const f16x8*)(Ah + arow * PLDA + ((lane >> 4) * 8));
            int brow = wn + i * 16 + (lane & 15);
            bf[i] = *(const f16x8*)(Bh + brow * PLDA + ((lane >> 4) * 8));
        }
        for (int i = 0; i < 4; ++i)
            for (int j = 0; j < 4; ++j)
                acc[i][j] = __builtin_amdgcn_mfma_f32_16x16x32_f16(af[i], bf[j], acc[i][j], 0, 0, 0);
        __syncthreads();
    }

    for (int i = 0; i < 4; ++i) {
        for (int j = 0; j < 4; ++j) {
            int jg = nt * 128 + wn + j * 16 + (lane & 15);
            float bv = bi[jg];
            for (int r = 0; r < 4; ++r) {
                int mg = mt * 128 + wm + i * 16 + (lane >> 4) * 4 + r;
                xs[(size_t)mg * 512 + jg] = acc[i][j][r] + bv;
            }
        }
    }
}

// ---------------- recurrence ----------------
#define WH_LDA 520   // 512 + 8 f16 -> 1040B row stride
#define HS_LDA 264   // 256 + 8 f16 -> 528B row stride

__device__ inline void unpack_to_lds(u32x4 v, f16* dh, f16* dl) {
    unsigned h01 = (v.x & 0xffffu) | (v.y << 16);
    unsigned h23 = (v.z & 0xffffu) | (v.w << 16);
    unsigned l01 = (v.x >> 16) | (v.y & 0xffff0000u);
    unsigned l23 = (v.z >> 16) | (v.w & 0xffff0000u);
    u32x2 hh = {h01, h23}, ll = {l01, l23};
    *(u32x2*)dh = hh;
    *(u32x2*)dl = ll;
}

__device__ inline void mfma_half(const f16* hhi, const f16* hlo, const f16* wh,
                                 int lane, int jl0, int kh,
                                 f32x4& acc0, f32x4& acc1) {
    for (int kc = 0; kc < 8; ++kc) {
        int klocal = kc * 32 + ((lane >> 4) * 8);
        f16x8 ahi = *(const f16x8*)(hhi + (lane & 15) * HS_LDA + klocal);
        f16x8 alo = *(const f16x8*)(hlo + (lane & 15) * HS_LDA + klocal);
        int kglob = kh * 256 + klocal;
        f16x8 bf0 = *(const f16x8*)(wh + (size_t)jl0 * WH_LDA + kglob);
        f16x8 bf1 = *(const f16x8*)(wh + (size_t)(jl0 + 16) * WH_LDA + kglob);
        acc0 = __builtin_amdgcn_mfma_f32_16x16x32_f16(ahi, bf0, acc0, 0, 0, 0);
        acc0 = __builtin_amdgcn_mfma_f32_16x16x32_f16(alo, bf0, acc0, 0, 0, 0);
        acc1 = __builtin_amdgcn_mfma_f32_16x16x32_f16(ahi, bf1, acc1, 0, 0, 0);
        acc1 = __builtin_amdgcn_mfma_f32_16x16x32_f16(alo, bf1, acc1, 0, 0, 0);
    }
}

__global__ __launch_bounds__(256)
void rnn_rec(const float* __restrict__ h0, const f16* __restrict__ w16base,
             const float* __restrict__ bh_f, const float* __restrict__ bh_b,
             float* xsF, float* xsB, unsigned* flags)
{
    extern __shared__ char smem[];
    f16* wh  = (f16*)smem;                          // 128 x WH_LDA
    f16* hhi = (f16*)(smem + 128 * WH_LDA * 2);     // 16 x HS_LDA
    f16* hlo = hhi + 16 * HS_LDA;                   // 16 x HS_LDA

    int bid = blockIdx.x;              // bid = slice*8 + dg: ring dg on one XCD (heuristic only)
    int dg = bid & 7, slice = bid >> 3;
    int dir = dg >> 2, g = dg & 3;

    float* xs = dir ? xsB : xsF;
    const f16* Wh16 = w16base + 262144 + (dir ? 2 * 262144 : 0);
    const float* bh = dir ? bh_b : bh_f;
    int b0 = g * 16;
    int tid = threadIdx.x, lane = tid & 63, w = tid >> 6;

    // load Wh slice rows [slice*128, +128) into LDS
    for (int it = 0; it < 32; ++it) {
        int idx = tid + it * 256;
        int row = idx >> 6, slot = idx & 63;
        uint4 v = *(const uint4*)(Wh16 + (size_t)(slice * 128 + row) * 512 + slot * 8);
        *(uint4*)(wh + row * WH_LDA + slot * 8) = v;
    }

    int jl0 = w * 32 + (lane & 15);
    int jg0 = slice * 128 + jl0;
    int jg1 = jg0 + 16;
    float bh0 = bh[jg0], bh1 = bh[jg1];
    int rbase = (lane >> 4) * 4;

    __syncthreads();

    unsigned* gflags = flags + (size_t)dg * 1024 * 4;
    unsigned* xsu = (unsigned*)xs;

    for (int st = 0; st < 1024; ++st) {
        int tt = dir ? 1023 - st : st;
        int ttp = dir ? tt + 1 : tt - 1;

        // prefetch xt (this WG's own lines; written only at step tt by us)
        float xt0[4], xt1[4];
        for (int r = 0; r < 4; ++r) {
            size_t base = ((size_t)(b0 + rbase + r) * 1024 + tt) * 512;
            xt0[r] = xs[base + jg0];
            xt1[r] = xs[base + jg1];
        }

        f32x4 acc0 = {0.f, 0.f, 0.f, 0.f}, acc1 = {0.f, 0.f, 0.f, 0.f};

        if (st > 0) {
            // acquire: poll previous step's 4 slice flags via L3
            if (tid < 4) {
                const unsigned* f = gflags + (size_t)(st - 1) * 4 + tid;
                while (ld_cg_u32(f) == 0u) {}
            }
            RAW_BAR;

            auto staddr = [&](int i, int h) -> const unsigned* {
                int idx = tid + i * 256;
                int row = idx >> 6, c = idx & 63;
                return xsu + ((size_t)(b0 + row) * 1024 + ttp) * 512 + (size_t)(c + h * 64) * 4;
            };

            u32x4 r0, r1, r2, r3, r4, r5, r6, r7;
            ld_cg_8x4(staddr(0, 0), staddr(1, 0), staddr(2, 0), staddr(3, 0),
                      staddr(0, 1), staddr(1, 1), staddr(2, 1), staddr(3, 1),
                      r0, r1, r2, r3, r4, r5, r6, r7);

            // unpack half 0 (k 0..255)
            { int idx = tid;       int row = idx >> 6, c = idx & 63; unpack_to_lds(r0, hhi + row * HS_LDA + c * 4, hlo + row * HS_LDA + c * 4); }
            { int idx = tid + 256; int row = idx >> 6, c = idx & 63; unpack_to_lds(r1, hhi + row * HS_LDA + c * 4, hlo + row * HS_LDA + c * 4); }
            { int idx = tid + 512; int row = idx >> 6, c = idx & 63; unpack_to_lds(r2, hhi + row * HS_LDA + c * 4, hlo + row * HS_LDA + c * 4); }
            { int idx = tid + 768; int row = idx >> 6, c = idx & 63; unpack_to_lds(r3, hhi + row * HS_LDA + c * 4, hlo + row * HS_LDA + c * 4); }
            WAIT_LGKM0;
            RAW_BAR;

            mfma_half(hhi, hlo, wh, lane, jl0, 0, acc0, acc1);
            WAIT_LGKM0;
            RAW_BAR;           // all reads of half-0 planes done

            WAIT_VM0;          // r4..r7 ready
            { int idx = tid;       int row = idx >> 6, c = idx & 63; unpack_to_lds(r4, hhi + row * HS_LDA + c * 4, hlo + row * HS_LDA + c * 4); }
            { int idx = tid + 256; int row = idx >> 6, c = idx & 63; unpack_to_lds(r5, hhi + row * HS_LDA + c * 4, hlo + row * HS_LDA + c * 4); }
            { int idx = tid + 512; int row = idx >> 6, c = idx & 63; unpack_to_lds(r6, hhi + row * HS_LDA + c * 4, hlo + row * HS_LDA + c * 4); }
            { int idx = tid + 768; int row = idx >> 6, c = idx & 63; unpack_to_lds(r7, hhi + row * HS_LDA + c * 4, hlo + row * HS_LDA + c * 4); }
            WAIT_LGKM0;
            RAW_BAR;

            mfma_half(hhi, hlo, wh, lane, jl0, 1, acc0, acc1);
        } else {
            // step 0: h0 from global (input array, plain cached loads)
            for (int kh = 0; kh < 2; ++kh) {
                for (int it = 0; it < 4; ++it) {
                    int idx = tid + it * 256;
                    int row = idx >> 6, col = idx & 63;
                    float4 v = *(const float4*)(h0 + (size_t)(b0 + row) * 512 + kh * 256 + col * 4);
                    float vv[4] = {v.x, v.y, v.z, v.w};
                    f16* dh = hhi + row * HS_LDA + col * 4;
                    f16* dl = hlo + row * HS_LDA + col * 4;
                    for (int q = 0; q < 4; ++q) {
                        f16 h_ = (f16)vv[q];
                        dh[q] = h_;
                        dl[q] = (f16)(vv[q] - (float)h_);
                    }
                }
                __syncthreads();
                mfma_half(hhi, hlo, wh, lane, jl0, kh, acc0, acc1);
                __syncthreads();
            }
        }

        // epilogue: h = tanh(Wh.h + xt + bh); write packed hi/lo through to L3
        for (int r = 0; r < 4; ++r) {
            size_t base = ((size_t)(b0 + rbase + r) * 1024 + tt) * 512;
            float h0v = fast_tanh(acc0[r] + xt0[r] + bh0);
            float h1v = fast_tanh(acc1[r] + xt1[r] + bh1);
            st_cg_u32(xsu + base + jg0, pack_hilo(h0v));
            st_cg_u32(xsu + base + jg1, pack_hilo(h1v));
        }
        WAIT_VM0;              // our stores are at the coherence point
        RAW_BAR;               // ... for every wave in the WG
        if (tid == 0)
            st_cg_u32(gflags + (size_t)st * 4 + slice, 1u);
    }
}

// ---------------- merge: out = h_f + h_b (both stored packed hi/lo) ----------------
__device__ inline float unpack_sum(unsigned u) {
    unsigned short hb = (unsigned short)(u & 0xffffu);
    unsigned short lb = (unsigned short)(u >> 16);
    return (float)__builtin_bit_cast(f16, hb) + (float)__builtin_bit_cast(f16, lb);
}

__global__ __launch_bounds__(256)
void merge_out(const unsigned* xsF, const unsigned* xsB, float* out)
{
    size_t i = ((size_t)blockIdx.x * 256 + threadIdx.x) * 4;
    size_t stride = (size_t)gridDim.x * 1024;
    for (; i < 33554432ULL; i += stride) {
        u32x4 a, b;
        ld_cg_2x4(xsF + i, xsB + i, a, b);
        float4 o;
        o.x = unpack_sum(a.x) + unpack_sum(b.x);
        o.y = unpack_sum(a.y) + unpack_sum(b.y);
        o.z = unpack_sum(a.z) + unpack_sum(b.z);
        o.w = unpack_sum(a.w) + unpack_sum(b.w);
        *(float4*)(out + i) = o;
    }
}

__global__ __launch_bounds__(256)
void copy_hidden(const float* __restrict__ hs, float* __restrict__ out)
{
    size_t i = (size_t)blockIdx.x * 256 + threadIdx.x;
    if (i < 32768) out[33554432ULL + i] = hs[i];
}

// ---------------- launch ----------------
extern "C" void kernel_launch(void* const* d_in, const int* in_sizes, int n_in,
                              void* d_out, int out_size, void* d_ws, size_t ws_size,
                              hipStream_t stream) {
    const float* x    = (const float*)d_in[0];
    const float* hs   = (const float*)d_in[1];
    const float* Wi_f = (const float*)d_in[2];
    const float* bi_f = (const float*)d_in[3];
    const float* Wh_f = (const float*)d_in[4];
    const float* bh_f = (const float*)d_in[5];
    const float* Wi_b = (const float*)d_in[6];
    const float* bi_b = (const float*)d_in[7];
    const float* Wh_b = (const float*)d_in[8];
    const float* bh_b = (const float*)d_in[9];

    float* out = (float*)d_out;
    char* ws = (char*)d_ws;

    float* xsF = out;                           // forward history lives in d_out
    float* xsB = (float*)(ws + XSB_OFF);
    f16* w16   = (f16*)(ws + W16_OFF);
    unsigned* flags = (unsigned*)(ws + FLAG_OFF);

    hipMemsetAsync(flags, 0, FLAG_BYTES, stream);
    cvt_w<<<1024, 256, 0, stream>>>(Wi_f, Wh_f, Wi_b, Wh_b, w16);
    proj<<<4096, 256, 0, stream>>>(x, w16, bi_f, bi_b, xsF, xsB);

    (void)hipFuncSetAttribute((const void*)rnn_rec,
                              hipFuncAttributeMaxDynamicSharedMemorySize, 150016);
    rnn_rec<<<32, 256, 150016, stream>>>(hs, w16, bh_f, bh_b, xsF, xsB, flags);

    merge_out<<<2048, 256, 0, stream>>>((const unsigned*)xsF, (const unsigned*)xsB, out);
    copy_hidden<<<128, 256, 0, stream>>>(hs, out);
}

// Round 4
// 3586.914 us; speedup vs baseline: 2.0895x; 1.1163x over previous
//
#include <hip/hip_runtime.h>
#include <math.h>

typedef _Float16 f16;
using f16x8 = __attribute__((ext_vector_type(8))) _Float16;
using f32x4 = __attribute__((ext_vector_type(4))) float;
using u32x4 = __attribute__((ext_vector_type(4))) unsigned;
using u32x2 = __attribute__((ext_vector_type(2))) unsigned;

// Problem sizes (fixed)
#define NB 64
#define NS 1024
#define NDIM 512
#define NH 512

// ws layout (bytes): xsB | w16 (Wi_f,Wh_f,Wi_b,Wh_b f16)
#define XSB_OFF   0ULL
#define W16_OFF   134217728ULL

// Tag bit: bit16 of each packed word (LSB of the lo-f16).
//   proj output (xt encoding):  bit16 = 0
//   rnn_rec output (h encoding): bit16 = 1
// Poison 0xAAAAAAAA has bit16 = 0 -> rejected by the h-poll.
#define TAG_BIT 0x00010000u

// ---------------- device-coherent (IC-direct) memory helpers ----------------
// sc0 sc1 ops commit to / read from the Infinity Cache: device-scope,
// placement-independent. Validated in round 2.

__device__ inline void st_ic_u32(unsigned* p, unsigned v) {
    asm volatile("global_store_dword %0, %1, off sc0 sc1"
                 :: "v"(p), "v"(v) : "memory");
}

// 8 x dwordx4, wait all.
__device__ inline void ld_ic_8x4(const unsigned* p0, const unsigned* p1,
                                 const unsigned* p2, const unsigned* p3,
                                 const unsigned* p4, const unsigned* p5,
                                 const unsigned* p6, const unsigned* p7,
                                 u32x4& r0, u32x4& r1, u32x4& r2, u32x4& r3,
                                 u32x4& r4, u32x4& r5, u32x4& r6, u32x4& r7) {
    asm volatile(
        "global_load_dwordx4 %0, %8, off sc0 sc1\n\t"
        "global_load_dwordx4 %1, %9, off sc0 sc1\n\t"
        "global_load_dwordx4 %2, %10, off sc0 sc1\n\t"
        "global_load_dwordx4 %3, %11, off sc0 sc1\n\t"
        "global_load_dwordx4 %4, %12, off sc0 sc1\n\t"
        "global_load_dwordx4 %5, %13, off sc0 sc1\n\t"
        "global_load_dwordx4 %6, %14, off sc0 sc1\n\t"
        "global_load_dwordx4 %7, %15, off sc0 sc1\n\t"
        "s_waitcnt vmcnt(0)"
        : "=&v"(r0), "=&v"(r1), "=&v"(r2), "=&v"(r3),
          "=&v"(r4), "=&v"(r5), "=&v"(r6), "=&v"(r7)
        : "v"(p0), "v"(p1), "v"(p2), "v"(p3),
          "v"(p4), "v"(p5), "v"(p6), "v"(p7)
        : "memory");
    __builtin_amdgcn_sched_barrier(0);
}

__device__ inline void ld_ic_2x4(const unsigned* pa, const unsigned* pb,
                                 u32x4& a, u32x4& b) {
    asm volatile(
        "global_load_dwordx4 %0, %2, off sc0 sc1\n\t"
        "global_load_dwordx4 %1, %3, off sc0 sc1\n\t"
        "s_waitcnt vmcnt(0)"
        : "=&v"(a), "=&v"(b)
        : "v"(pa), "v"(pb)
        : "memory");
    __builtin_amdgcn_sched_barrier(0);
}

#define WAIT_LGKM0 do { asm volatile("s_waitcnt lgkmcnt(0)" ::: "memory"); \
                        __builtin_amdgcn_sched_barrier(0); } while (0)
#define RAW_BAR    do { __builtin_amdgcn_s_barrier(); \
                        __builtin_amdgcn_sched_barrier(0); } while (0)

__device__ inline float fast_tanh(float y) {
    // tanh(y) = 1 - 2/(exp2(2*log2e*y)+1); exact at both saturating tails.
    float t = __builtin_amdgcn_exp2f(y * 2.8853900817779268f);
    return 1.0f - 2.0f * __builtin_amdgcn_rcpf(t + 1.0f);
}

// packed {hi,lo} f16 pair encodings
__device__ inline unsigned pack_xt(float v) {          // tag bit forced 0
    f16 hi = (f16)v;
    f16 lo = (f16)(v - (float)hi);
    unsigned w = ((unsigned)__builtin_bit_cast(unsigned short, lo) << 16) |
                 (unsigned)__builtin_bit_cast(unsigned short, hi);
    return w & ~TAG_BIT;
}
__device__ inline unsigned pack_h(float v) {           // tag bit forced 1
    f16 hi = (f16)v;
    f16 lo = (f16)(v - (float)hi);
    unsigned w = ((unsigned)__builtin_bit_cast(unsigned short, lo) << 16) |
                 (unsigned)__builtin_bit_cast(unsigned short, hi);
    return w | TAG_BIT;
}
__device__ inline float unpack_sum(unsigned u) {       // hi + lo (tag included in lo: negligible)
    unsigned short hb = (unsigned short)(u & 0xffffu);
    unsigned short lb = (unsigned short)(u >> 16);
    return (float)__builtin_bit_cast(f16, hb) + (float)__builtin_bit_cast(f16, lb);
}

// ---------------- weight conversion fp32 -> fp16 ----------------
__global__ __launch_bounds__(256) void cvt_w(const float* __restrict__ wi_f,
                                             const float* __restrict__ wh_f,
                                             const float* __restrict__ wi_b,
                                             const float* __restrict__ wh_b,
                                             f16* __restrict__ o) {
    int i = blockIdx.x * 256 + threadIdx.x;
    if (i < 512 * 512) {
        o[i]              = (f16)wi_f[i];
        o[262144 + i]     = (f16)wh_f[i];
        o[2 * 262144 + i] = (f16)wi_b[i];
        o[3 * 262144 + i] = (f16)wh_b[i];
    }
}

// ---------------- input projection GEMM ----------------
// xs[dir] = pack_xt(x @ Wi^T + bi).  M=65536, N=512, K=512. 128x128 tile, BK=32.
#define PLDA 40  // padded row (f16 elems)

__global__ __launch_bounds__(256)
void proj(const float* __restrict__ x, const f16* __restrict__ w16base,
          const float* __restrict__ bi_f, const float* __restrict__ bi_b,
          unsigned* __restrict__ xsF, unsigned* __restrict__ xsB)
{
    __shared__ f16 Ah[128 * PLDA];
    __shared__ f16 Bh[128 * PLDA];

    int bidx = blockIdx.x;
    int dir = bidx >> 11;
    int rem = bidx & 2047;
    int mt = rem >> 2, nt = rem & 3;

    const f16* Wi16 = w16base + (dir ? 2 * 262144 : 0);
    const float* bi = dir ? bi_b : bi_f;
    unsigned* xs = dir ? xsB : xsF;

    int tid = threadIdx.x;
    int lane = tid & 63, w = tid >> 6;
    int wm = (w >> 1) * 64, wn = (w & 1) * 64;

    f32x4 acc[4][4] = {};

    for (int ks = 0; ks < 16; ++ks) {
        int k0 = ks * 32;
        for (int it = 0; it < 4; ++it) {
            int idx = tid + it * 256;
            int row = idx >> 3, slot = idx & 7;
            float4 v = *(const float4*)(x + (size_t)(mt * 128 + row) * 512 + k0 + slot * 4);
            f16* dst = Ah + row * PLDA + slot * 4;
            dst[0] = (f16)v.x; dst[1] = (f16)v.y; dst[2] = (f16)v.z; dst[3] = (f16)v.w;
        }
        for (int it = 0; it < 2; ++it) {
            int idx = tid + it * 256;
            int row = idx >> 2, slot = idx & 3;
            uint4 v = *(const uint4*)(Wi16 + (size_t)(nt * 128 + row) * 512 + k0 + slot * 8);
            *(uint4*)(Bh + row * PLDA + slot * 8) = v;
        }
        __syncthreads();

        f16x8 af[4], bf[4];
        for (int i = 0; i < 4; ++i) {
            int arow = wm + i * 16 + (lane & 15);
            af[i] = *(const f16x8*)(Ah + arow * PLDA + ((lane >> 4) * 8));
            int brow = wn + i * 16 + (lane & 15);
            bf[i] = *(const f16x8*)(Bh + brow * PLDA + ((lane >> 4) * 8));
        }
        for (int i = 0; i < 4; ++i)
            for (int j = 0; j < 4; ++j)
                acc[i][j] = __builtin_amdgcn_mfma_f32_16x16x32_f16(af[i], bf[j], acc[i][j], 0, 0, 0);
        __syncthreads();
    }

    for (int i = 0; i < 4; ++i) {
        for (int j = 0; j < 4; ++j) {
            int jg = nt * 128 + wn + j * 16 + (lane & 15);
            float bv = bi[jg];
            for (int r = 0; r < 4; ++r) {
                int mg = mt * 128 + wm + i * 16 + (lane >> 4) * 4 + r;
                xs[(size_t)mg * 512 + jg] = pack_xt(acc[i][j][r] + bv);
            }
        }
    }
}

// ---------------- recurrence ----------------
#define WH_LDA 520   // 512 + 8 f16 -> 1040B row stride
#define HS_LDA 264   // 256 + 8 f16 -> 528B row stride

// split packed words into hi/lo f16 planes, one b64 write each
__device__ inline void unpack_to_lds(u32x4 v, f16* dh, f16* dl) {
    unsigned h01 = (v.x & 0xffffu) | (v.y << 16);
    unsigned h23 = (v.z & 0xffffu) | (v.w << 16);
    unsigned l01 = (v.x >> 16) | (v.y & 0xffff0000u);
    unsigned l23 = (v.z >> 16) | (v.w & 0xffff0000u);
    u32x2 hh = {h01, h23}, ll = {l01, l23};
    *(u32x2*)dh = hh;
    *(u32x2*)dl = ll;
}

__device__ inline void mfma_half(const f16* hhi, const f16* hlo, const f16* wh,
                                 int lane, int jl0, int kh,
                                 f32x4& acc0, f32x4& acc1) {
    for (int kc = 0; kc < 8; ++kc) {
        int klocal = kc * 32 + ((lane >> 4) * 8);
        f16x8 ahi = *(const f16x8*)(hhi + (lane & 15) * HS_LDA + klocal);
        f16x8 alo = *(const f16x8*)(hlo + (lane & 15) * HS_LDA + klocal);
        int kglob = kh * 256 + klocal;
        f16x8 bf0 = *(const f16x8*)(wh + (size_t)jl0 * WH_LDA + kglob);
        f16x8 bf1 = *(const f16x8*)(wh + (size_t)(jl0 + 16) * WH_LDA + kglob);
        acc0 = __builtin_amdgcn_mfma_f32_16x16x32_f16(ahi, bf0, acc0, 0, 0, 0);
        acc0 = __builtin_amdgcn_mfma_f32_16x16x32_f16(alo, bf0, acc0, 0, 0, 0);
        acc1 = __builtin_amdgcn_mfma_f32_16x16x32_f16(ahi, bf1, acc1, 0, 0, 0);
        acc1 = __builtin_amdgcn_mfma_f32_16x16x32_f16(alo, bf1, acc1, 0, 0, 0);
    }
}

__global__ __launch_bounds__(256)
void rnn_rec(const float* __restrict__ h0, const f16* __restrict__ w16base,
             const float* __restrict__ bh_f, const float* __restrict__ bh_b,
             unsigned* xsF, unsigned* xsB)
{
    extern __shared__ char smem[];
    f16* wh  = (f16*)smem;                          // 128 x WH_LDA
    f16* hhi = (f16*)(smem + 128 * WH_LDA * 2);     // 16 x HS_LDA
    f16* hlo = hhi + 16 * HS_LDA;                   // 16 x HS_LDA

    int bid = blockIdx.x;
    int dg = bid & 7, slice = bid >> 3;
    int dir = dg >> 2, g = dg & 3;

    unsigned* xsu = dir ? xsB : xsF;
    const f16* Wh16 = w16base + 262144 + (dir ? 2 * 262144 : 0);
    const float* bh = dir ? bh_b : bh_f;
    int b0 = g * 16;
    int tid = threadIdx.x, lane = tid & 63, w = tid >> 6;

    // load Wh slice rows [slice*128, +128) into LDS
    for (int it = 0; it < 32; ++it) {
        int idx = tid + it * 256;
        int row = idx >> 6, slot = idx & 63;
        uint4 v = *(const uint4*)(Wh16 + (size_t)(slice * 128 + row) * 512 + slot * 8);
        *(uint4*)(wh + row * WH_LDA + slot * 8) = v;
    }

    int jl0 = w * 32 + (lane & 15);
    int jg0 = slice * 128 + jl0;
    int jg1 = jg0 + 16;
    float bh0 = bh[jg0], bh1 = bh[jg1];
    int rbase = (lane >> 4) * 4;

    // per-thread h-load addresses (row/col fixed; only t varies)
    int hrow = tid >> 6;        // wait: recomputed below per it; kept simple
    (void)hrow;

    __syncthreads();

    for (int st = 0; st < 1024; ++st) {
        int tt = dir ? 1023 - st : st;
        int ttp = dir ? tt + 1 : tt - 1;

        // prefetch xt words (this WG's own lines, still xt-encoded; plain cached loads)
        unsigned xtw0[4], xtw1[4];
        for (int r = 0; r < 4; ++r) {
            size_t base = ((size_t)(b0 + rbase + r) * 1024 + tt) * 512;
            xtw0[r] = xsu[base + jg0];
            xtw1[r] = xsu[base + jg1];
        }

        f32x4 acc0 = {0.f, 0.f, 0.f, 0.f}, acc1 = {0.f, 0.f, 0.f, 0.f};

        if (st > 0) {
            // poll h(ttp): all 512 cols, 8 x uint4 per thread, self-validating tags
            auto staddr = [&](int i, int h) -> const unsigned* {
                int idx = tid + i * 256;
                int row = idx >> 6, c = idx & 63;
                return xsu + ((size_t)(b0 + row) * 1024 + ttp) * 512 + (size_t)(c + h * 64) * 4;
            };
            const unsigned* p0 = staddr(0, 0); const unsigned* p1 = staddr(1, 0);
            const unsigned* p2 = staddr(2, 0); const unsigned* p3 = staddr(3, 0);
            const unsigned* p4 = staddr(0, 1); const unsigned* p5 = staddr(1, 1);
            const unsigned* p6 = staddr(2, 1); const unsigned* p7 = staddr(3, 1);

            u32x4 r0, r1, r2, r3, r4, r5, r6, r7;
            for (;;) {
                ld_ic_8x4(p0, p1, p2, p3, p4, p5, p6, p7,
                          r0, r1, r2, r3, r4, r5, r6, r7);
                unsigned m = r0.x & r0.y & r0.z & r0.w;
                m &= r1.x & r1.y & r1.z & r1.w;
                m &= r2.x & r2.y & r2.z & r2.w;
                m &= r3.x & r3.y & r3.z & r3.w;
                m &= r4.x & r4.y & r4.z & r4.w;
                m &= r5.x & r5.y & r5.z & r5.w;
                m &= r6.x & r6.y & r6.z & r6.w;
                m &= r7.x & r7.y & r7.z & r7.w;
                if (m & TAG_BIT) break;
            }

            // deposit half 0 (k 0..255)
            { int idx = tid;       int row = idx >> 6, c = idx & 63; unpack_to_lds(r0, hhi + row * HS_LDA + c * 4, hlo + row * HS_LDA + c * 4); }
            { int idx = tid + 256; int row = idx >> 6, c = idx & 63; unpack_to_lds(r1, hhi + row * HS_LDA + c * 4, hlo + row * HS_LDA + c * 4); }
            { int idx = tid + 512; int row = idx >> 6, c = idx & 63; unpack_to_lds(r2, hhi + row * HS_LDA + c * 4, hlo + row * HS_LDA + c * 4); }
            { int idx = tid + 768; int row = idx >> 6, c = idx & 63; unpack_to_lds(r3, hhi + row * HS_LDA + c * 4, hlo + row * HS_LDA + c * 4); }
            WAIT_LGKM0;
            RAW_BAR;

            mfma_half(hhi, hlo, wh, lane, jl0, 0, acc0, acc1);
            WAIT_LGKM0;
            RAW_BAR;           // half-0 plane reads complete

            // deposit half 1 (k 256..511)
            { int idx = tid;       int row = idx >> 6, c = idx & 63; unpack_to_lds(r4, hhi + row * HS_LDA + c * 4, hlo + row * HS_LDA + c * 4); }
            { int idx = tid + 256; int row = idx >> 6, c = idx & 63; unpack_to_lds(r5, hhi + row * HS_LDA + c * 4, hlo + row * HS_LDA + c * 4); }
            { int idx = tid + 512; int row = idx >> 6, c = idx & 63; unpack_to_lds(r6, hhi + row * HS_LDA + c * 4, hlo + row * HS_LDA + c * 4); }
            { int idx = tid + 768; int row = idx >> 6, c = idx & 63; unpack_to_lds(r7, hhi + row * HS_LDA + c * 4, hlo + row * HS_LDA + c * 4); }
            WAIT_LGKM0;
            RAW_BAR;

            mfma_half(hhi, hlo, wh, lane, jl0, 1, acc0, acc1);
            WAIT_LGKM0;
            RAW_BAR;           // planes free for next iteration
        } else {
            // step 0: h0 from global (input array, plain cached loads)
            for (int kh = 0; kh < 2; ++kh) {
                for (int it = 0; it < 4; ++it) {
                    int idx = tid + it * 256;
                    int row = idx >> 6, col = idx & 63;
                    float4 v = *(const float4*)(h0 + (size_t)(b0 + row) * 512 + kh * 256 + col * 4);
                    float vv[4] = {v.x, v.y, v.z, v.w};
                    f16* dh = hhi + row * HS_LDA + col * 4;
                    f16* dl = hlo + row * HS_LDA + col * 4;
                    for (int q = 0; q < 4; ++q) {
                        f16 h_ = (f16)vv[q];
                        dh[q] = h_;
                        dl[q] = (f16)(vv[q] - (float)h_);
                    }
                }
                __syncthreads();
                mfma_half(hhi, hlo, wh, lane, jl0, kh, acc0, acc1);
                __syncthreads();
            }
        }

        // epilogue: h = tanh(Wh.h + xt + bh); overwrite xt word with tagged h word.
        // Fire-and-forget sc1 stores: the data IS the signal.
        for (int r = 0; r < 4; ++r) {
            size_t base = ((size_t)(b0 + rbase + r) * 1024 + tt) * 512;
            float h0v = fast_tanh(acc0[r] + unpack_sum(xtw0[r]) + bh0);
            float h1v = fast_tanh(acc1[r] + unpack_sum(xtw1[r]) + bh1);
            st_ic_u32(xsu + base + jg0, pack_h(h0v));
            st_ic_u32(xsu + base + jg1, pack_h(h1v));
        }
    }
}

// ---------------- merge: out = h_f + h_b (both stored packed hi/lo) ----------------
__global__ __launch_bounds__(256)
void merge_out(const unsigned* xsF, const unsigned* xsB, float* out)
{
    size_t i = ((size_t)blockIdx.x * 256 + threadIdx.x) * 4;
    size_t stride = (size_t)gridDim.x * 1024;
    for (; i < 33554432ULL; i += stride) {
        u32x4 a, b;
        ld_ic_2x4(xsF + i, xsB + i, a, b);
        float4 o;
        o.x = unpack_sum(a.x) + unpack_sum(b.x);
        o.y = unpack_sum(a.y) + unpack_sum(b.y);
        o.z = unpack_sum(a.z) + unpack_sum(b.z);
        o.w = unpack_sum(a.w) + unpack_sum(b.w);
        *(float4*)(out + i) = o;
    }
}

__global__ __launch_bounds__(256)
void copy_hidden(const float* __restrict__ hs, float* __restrict__ out)
{
    size_t i = (size_t)blockIdx.x * 256 + threadIdx.x;
    if (i < 32768) out[33554432ULL + i] = hs[i];
}

// ---------------- launch ----------------
extern "C" void kernel_launch(void* const* d_in, const int* in_sizes, int n_in,
                              void* d_out, int out_size, void* d_ws, size_t ws_size,
                              hipStream_t stream) {
    const float* x    = (const float*)d_in[0];
    const float* hs   = (const float*)d_in[1];
    const float* Wi_f = (const float*)d_in[2];
    const float* bi_f = (const float*)d_in[3];
    const float* Wh_f = (const float*)d_in[4];
    const float* bh_f = (const float*)d_in[5];
    const float* Wi_b = (const float*)d_in[6];
    const float* bi_b = (const float*)d_in[7];
    const float* Wh_b = (const float*)d_in[8];
    const float* bh_b = (const float*)d_in[9];

    float* out = (float*)d_out;
    char* ws = (char*)d_ws;

    unsigned* xsF = (unsigned*)out;             // forward history lives in d_out
    unsigned* xsB = (unsigned*)(ws + XSB_OFF);
    f16* w16      = (f16*)(ws + W16_OFF);

    cvt_w<<<1024, 256, 0, stream>>>(Wi_f, Wh_f, Wi_b, Wh_b, w16);
    proj<<<4096, 256, 0, stream>>>(x, w16, bi_f, bi_b, xsF, xsB);

    (void)hipFuncSetAttribute((const void*)rnn_rec,
                              hipFuncAttributeMaxDynamicSharedMemorySize, 150016);
    rnn_rec<<<32, 256, 150016, stream>>>(hs, w16, bh_f, bh_b, xsF, xsB);

    merge_out<<<2048, 256, 0, stream>>>(xsF, xsB, out);
    copy_hidden<<<128, 256, 0, stream>>>(hs, out);
}

// Round 5
// 2684.433 us; speedup vs baseline: 2.7920x; 1.3362x over previous
//
#include <hip/hip_runtime.h>
#include <math.h>

typedef _Float16 f16;
using f16x8 = __attribute__((ext_vector_type(8))) _Float16;
using f32x4 = __attribute__((ext_vector_type(4))) float;
using u32x4 = __attribute__((ext_vector_type(4))) unsigned;
using u32x2 = __attribute__((ext_vector_type(2))) unsigned;

// Problem sizes (fixed)
#define NB 64
#define NS 1024
#define NDIM 512
#define NH 512

// ws layout (bytes): xsB | w16 (Wi_f,Wh_f,Wi_b,Wh_b f16)
#define XSB_OFF   0ULL
#define W16_OFF   134217728ULL

// Tag bit: bit16 of each packed word (LSB of the lo-f16).
//   proj output (xt): bit16 = 0;  rnn_rec output (h): bit16 = 1.
// Poison 0xAAAAAAAA has bit16=0 -> rejected. proj fully overwrites both xs
// buffers every replay, resetting all tags to 0 (replay-safe).
#define TAG_BIT 0x00010000u

// ---------------- device-coherent (IC-direct) memory helpers ----------------
__device__ inline void st_ic_u32(unsigned* p, unsigned v) {
    asm volatile("global_store_dword %0, %1, off sc0 sc1"
                 :: "v"(p), "v"(v) : "memory");
}

// issue 8 dwordx4 IC loads, NO wait (results valid only after a later claim)
__device__ inline void issue8(const unsigned* p0, const unsigned* p1,
                              const unsigned* p2, const unsigned* p3,
                              const unsigned* p4, const unsigned* p5,
                              const unsigned* p6, const unsigned* p7,
                              u32x4& r0, u32x4& r1, u32x4& r2, u32x4& r3,
                              u32x4& r4, u32x4& r5, u32x4& r6, u32x4& r7) {
    asm volatile(
        "global_load_dwordx4 %0, %8, off sc0 sc1\n\t"
        "global_load_dwordx4 %1, %9, off sc0 sc1\n\t"
        "global_load_dwordx4 %2, %10, off sc0 sc1\n\t"
        "global_load_dwordx4 %3, %11, off sc0 sc1\n\t"
        "global_load_dwordx4 %4, %12, off sc0 sc1\n\t"
        "global_load_dwordx4 %5, %13, off sc0 sc1\n\t"
        "global_load_dwordx4 %6, %14, off sc0 sc1\n\t"
        "global_load_dwordx4 %7, %15, off sc0 sc1"
        : "=&v"(r0), "=&v"(r1), "=&v"(r2), "=&v"(r3),
          "=&v"(r4), "=&v"(r5), "=&v"(r6), "=&v"(r7)
        : "v"(p0), "v"(p1), "v"(p2), "v"(p3),
          "v"(p4), "v"(p5), "v"(p6), "v"(p7)
        : "memory");
    __builtin_amdgcn_sched_barrier(0);
}

// wait until only the newest 8 VMEM ops are outstanding -> the window passed
// here (issued 8-ops ago) is complete. vmcnt retires in issue order (m135),
// so any older stores/loads are also complete. "+v" orders reg reads after it.
__device__ inline void claim8(u32x4& r0, u32x4& r1, u32x4& r2, u32x4& r3,
                              u32x4& r4, u32x4& r5, u32x4& r6, u32x4& r7) {
    asm volatile("s_waitcnt vmcnt(8)"
                 : "+v"(r0), "+v"(r1), "+v"(r2), "+v"(r3),
                   "+v"(r4), "+v"(r5), "+v"(r6), "+v"(r7)
                 :: "memory");
    __builtin_amdgcn_sched_barrier(0);
}

// full drain; keeps BOTH windows' registers alive until here so the pending
// window's hardware writebacks cannot corrupt reused registers.
__device__ inline void drain16(u32x4& a0, u32x4& a1, u32x4& a2, u32x4& a3,
                               u32x4& a4, u32x4& a5, u32x4& a6, u32x4& a7,
                               u32x4& b0, u32x4& b1, u32x4& b2, u32x4& b3,
                               u32x4& b4, u32x4& b5, u32x4& b6, u32x4& b7) {
    asm volatile("s_waitcnt vmcnt(0)"
                 : "+v"(a0), "+v"(a1), "+v"(a2), "+v"(a3),
                   "+v"(a4), "+v"(a5), "+v"(a6), "+v"(a7),
                   "+v"(b0), "+v"(b1), "+v"(b2), "+v"(b3),
                   "+v"(b4), "+v"(b5), "+v"(b6), "+v"(b7)
                 :: "memory");
    __builtin_amdgcn_sched_barrier(0);
}

#define WAIT_LGKM0 do { asm volatile("s_waitcnt lgkmcnt(0)" ::: "memory"); \
                        __builtin_amdgcn_sched_barrier(0); } while (0)
#define RAW_BAR    do { __builtin_amdgcn_s_barrier(); \
                        __builtin_amdgcn_sched_barrier(0); } while (0)

__device__ inline float fast_tanh(float y) {
    float t = __builtin_amdgcn_exp2f(y * 2.8853900817779268f);
    return 1.0f - 2.0f * __builtin_amdgcn_rcpf(t + 1.0f);
}

__device__ inline unsigned pack_xt(float v) {          // tag 0
    f16 hi = (f16)v;
    f16 lo = (f16)(v - (float)hi);
    unsigned w = ((unsigned)__builtin_bit_cast(unsigned short, lo) << 16) |
                 (unsigned)__builtin_bit_cast(unsigned short, hi);
    return w & ~TAG_BIT;
}
__device__ inline unsigned pack_h(float v) {           // tag 1
    f16 hi = (f16)v;
    f16 lo = (f16)(v - (float)hi);
    unsigned w = ((unsigned)__builtin_bit_cast(unsigned short, lo) << 16) |
                 (unsigned)__builtin_bit_cast(unsigned short, hi);
    return w | TAG_BIT;
}
__device__ inline float unpack_sum(unsigned u) {
    unsigned short hb = (unsigned short)(u & 0xffffu);
    unsigned short lb = (unsigned short)(u >> 16);
    return (float)__builtin_bit_cast(f16, hb) + (float)__builtin_bit_cast(f16, lb);
}

__device__ inline bool tags_ok(const u32x4& q0, const u32x4& q1, const u32x4& q2, const u32x4& q3,
                               const u32x4& q4, const u32x4& q5, const u32x4& q6, const u32x4& q7) {
    unsigned m = q0.x & q0.y & q0.z & q0.w;
    m &= q1.x & q1.y & q1.z & q1.w;
    m &= q2.x & q2.y & q2.z & q2.w;
    m &= q3.x & q3.y & q3.z & q3.w;
    m &= q4.x & q4.y & q4.z & q4.w;
    m &= q5.x & q5.y & q5.z & q5.w;
    m &= q6.x & q6.y & q6.z & q6.w;
    m &= q7.x & q7.y & q7.z & q7.w;
    return (m & TAG_BIT) != 0u;
}

// ---------------- weight conversion fp32 -> fp16 ----------------
__global__ __launch_bounds__(256) void cvt_w(const float* __restrict__ wi_f,
                                             const float* __restrict__ wh_f,
                                             const float* __restrict__ wi_b,
                                             const float* __restrict__ wh_b,
                                             f16* __restrict__ o) {
    int i = blockIdx.x * 256 + threadIdx.x;
    if (i < 512 * 512) {
        o[i]              = (f16)wi_f[i];
        o[262144 + i]     = (f16)wh_f[i];
        o[2 * 262144 + i] = (f16)wi_b[i];
        o[3 * 262144 + i] = (f16)wh_b[i];
    }
}

// ---------------- input projection GEMM ----------------
#define PLDA 40  // padded row (f16 elems)

__global__ __launch_bounds__(256)
void proj(const float* __restrict__ x, const f16* __restrict__ w16base,
          const float* __restrict__ bi_f, const float* __restrict__ bi_b,
          unsigned* __restrict__ xsF, unsigned* __restrict__ xsB)
{
    __shared__ f16 Ah[128 * PLDA];
    __shared__ f16 Bh[128 * PLDA];

    int bidx = blockIdx.x;
    int dir = bidx >> 11;
    int rem = bidx & 2047;
    int mt = rem >> 2, nt = rem & 3;

    const f16* Wi16 = w16base + (dir ? 2 * 262144 : 0);
    const float* bi = dir ? bi_b : bi_f;
    unsigned* xs = dir ? xsB : xsF;

    int tid = threadIdx.x;
    int lane = tid & 63, w = tid >> 6;
    int wm = (w >> 1) * 64, wn = (w & 1) * 64;

    f32x4 acc[4][4] = {};

    for (int ks = 0; ks < 16; ++ks) {
        int k0 = ks * 32;
        for (int it = 0; it < 4; ++it) {
            int idx = tid + it * 256;
            int row = idx >> 3, slot = idx & 7;
            float4 v = *(const float4*)(x + (size_t)(mt * 128 + row) * 512 + k0 + slot * 4);
            f16* dst = Ah + row * PLDA + slot * 4;
            dst[0] = (f16)v.x; dst[1] = (f16)v.y; dst[2] = (f16)v.z; dst[3] = (f16)v.w;
        }
        for (int it = 0; it < 2; ++it) {
            int idx = tid + it * 256;
            int row = idx >> 2, slot = idx & 3;
            uint4 v = *(const uint4*)(Wi16 + (size_t)(nt * 128 + row) * 512 + k0 + slot * 8);
            *(uint4*)(Bh + row * PLDA + slot * 8) = v;
        }
        __syncthreads();

        f16x8 af[4], bf[4];
        for (int i = 0; i < 4; ++i) {
            int arow = wm + i * 16 + (lane & 15);
            af[i] = *(const f16x8*)(Ah + arow * PLDA + ((lane >> 4) * 8));
            int brow = wn + i * 16 + (lane & 15);
            bf[i] = *(const f16x8*)(Bh + brow * PLDA + ((lane >> 4) * 8));
        }
        for (int i = 0; i < 4; ++i)
            for (int j = 0; j < 4; ++j)
                acc[i][j] = __builtin_amdgcn_mfma_f32_16x16x32_f16(af[i], bf[j], acc[i][j], 0, 0, 0);
        __syncthreads();
    }

    for (int i = 0; i < 4; ++i) {
        for (int j = 0; j < 4; ++j) {
            int jg = nt * 128 + wn + j * 16 + (lane & 15);
            float bv = bi[jg];
            for (int r = 0; r < 4; ++r) {
                int mg = mt * 128 + wm + i * 16 + (lane >> 4) * 4 + r;
                xs[(size_t)mg * 512 + jg] = pack_xt(acc[i][j][r] + bv);
            }
        }
    }
}

// ---------------- recurrence ----------------
// 32 WGs: dir(2) x group(4 batches-of-16) x slice(4 j-chunks-of-128).
// Wh B-fragments register-resident (128 VGPR/lane); LDS holds only the
// hi-f16 h plane (16 x HS_LDA). h exchanged via IC with self-validating tags.
#define HS_LDA 520   // 512+8 f16 -> 1040B row stride (16B-aligned, 2-way banks)

__device__ inline void dep2(u32x4 v, f16* dst) {   // hi-halves of 4 words -> b64
    unsigned h01 = (v.x & 0xffffu) | (v.y << 16);
    unsigned h23 = (v.z & 0xffffu) | (v.w << 16);
    u32x2 hh = {h01, h23};
    *(u32x2*)dst = hh;
}

__global__ __launch_bounds__(256, 1)
void rnn_rec(const float* __restrict__ h0, const f16* __restrict__ w16base,
             const float* __restrict__ bh_f, const float* __restrict__ bh_b,
             unsigned* xsF, unsigned* xsB)
{
    __shared__ f16 hhi[16 * HS_LDA];

    int bid = blockIdx.x;
    int dg = bid & 7, slice = bid >> 3;
    int dir = dg >> 2, g = dg & 3;

    unsigned* xsu = dir ? xsB : xsF;
    const f16* Wh16 = w16base + 262144 + (dir ? 2 * 262144 : 0);
    const float* bh = dir ? bh_b : bh_f;
    int b0 = g * 16;
    int tid = threadIdx.x, lane = tid & 63, w = tid >> 6;
    int c = tid & 63;
    int row0 = tid >> 6;             // 0..3 (wave id)

    int jl0 = w * 32 + (lane & 15);
    int jg0 = slice * 128 + jl0;
    int jg1 = jg0 + 16;
    float bh0 = bh[jg0], bh1 = bh[jg1];
    int rbase = (lane >> 4) * 4;

    // ---- Wh B-fragments into registers (init, plain loads) ----
    f16x8 bf0[16], bf1[16];
    {
        const f16* wr0 = Wh16 + (size_t)jg0 * 512 + (lane >> 4) * 8;
        const f16* wr1 = Wh16 + (size_t)jg1 * 512 + (lane >> 4) * 8;
        #pragma unroll
        for (int kc = 0; kc < 16; ++kc) {
            bf0[kc] = *(const f16x8*)(wr0 + kc * 32);
            bf1[kc] = *(const f16x8*)(wr1 + kc * 32);
        }
    }

    const f16* arow = hhi + (lane & 15) * HS_LDA + (lane >> 4) * 8;

    for (int st = 0; st < 1024; ++st) {
        int tt = dir ? 1023 - st : st;
        int ttp = dir ? tt + 1 : tt - 1;

        // xt prefetch (plain cached loads; our own columns only)
        unsigned xtw0[4], xtw1[4];
        #pragma unroll
        for (int r = 0; r < 4; ++r) {
            size_t base = ((size_t)(b0 + rbase + r) * 1024 + tt) * 512;
            xtw0[r] = xsu[base + jg0];
            xtw1[r] = xsu[base + jg1];
        }

        f32x4 acc0 = {0.f, 0.f, 0.f, 0.f}, acc1 = {0.f, 0.f, 0.f, 0.f};

        if (st > 0) {
            const unsigned* p0 = xsu + ((size_t)(b0 + row0     ) * 1024 + ttp) * 512 + c * 4;
            const unsigned* p1 = xsu + ((size_t)(b0 + row0 +  4) * 1024 + ttp) * 512 + c * 4;
            const unsigned* p2 = xsu + ((size_t)(b0 + row0 +  8) * 1024 + ttp) * 512 + c * 4;
            const unsigned* p3 = xsu + ((size_t)(b0 + row0 + 12) * 1024 + ttp) * 512 + c * 4;
            const unsigned* p4 = p0 + 256;
            const unsigned* p5 = p1 + 256;
            const unsigned* p6 = p2 + 256;
            const unsigned* p7 = p3 + 256;

            u32x4 a0, a1, a2, a3, a4, a5, a6, a7;
            u32x4 q0, q1, q2, q3, q4, q5, q6, q7;

            f16* d0 = hhi + (row0     ) * HS_LDA + c * 4;
            f16* d1 = hhi + (row0 +  4) * HS_LDA + c * 4;
            f16* d2 = hhi + (row0 +  8) * HS_LDA + c * 4;
            f16* d3 = hhi + (row0 + 12) * HS_LDA + c * 4;

            issue8(p0, p1, p2, p3, p4, p5, p6, p7, a0, a1, a2, a3, a4, a5, a6, a7);
            for (;;) {
                issue8(p0, p1, p2, p3, p4, p5, p6, p7, q0, q1, q2, q3, q4, q5, q6, q7);
                claim8(a0, a1, a2, a3, a4, a5, a6, a7);
                if (tags_ok(a0, a1, a2, a3, a4, a5, a6, a7)) {
                    dep2(a0, d0); dep2(a1, d1); dep2(a2, d2); dep2(a3, d3);
                    dep2(a4, d0 + 256); dep2(a5, d1 + 256); dep2(a6, d2 + 256); dep2(a7, d3 + 256);
                    break;
                }
                issue8(p0, p1, p2, p3, p4, p5, p6, p7, a0, a1, a2, a3, a4, a5, a6, a7);
                claim8(q0, q1, q2, q3, q4, q5, q6, q7);
                if (tags_ok(q0, q1, q2, q3, q4, q5, q6, q7)) {
                    dep2(q0, d0); dep2(q1, d1); dep2(q2, d2); dep2(q3, d3);
                    dep2(q4, d0 + 256); dep2(q5, d1 + 256); dep2(q6, d2 + 256); dep2(q7, d3 + 256);
                    break;
                }
            }
            WAIT_LGKM0;          // deposits visible
            RAW_BAR;

            #pragma unroll
            for (int kc = 0; kc < 16; ++kc) {
                f16x8 a = *(const f16x8*)(arow + kc * 32);
                acc0 = __builtin_amdgcn_mfma_f32_16x16x32_f16(a, bf0[kc], acc0, 0, 0, 0);
                acc1 = __builtin_amdgcn_mfma_f32_16x16x32_f16(a, bf1[kc], acc1, 0, 0, 0);
            }

            // drain the still-pending window while MFMA latency retires;
            // keeps both windows' registers pinned until no writebacks remain.
            drain16(a0, a1, a2, a3, a4, a5, a6, a7, q0, q1, q2, q3, q4, q5, q6, q7);
            RAW_BAR;             // plane reads complete WG-wide
        } else {
            // step 0: stage h0 hi-f16 into the plane (plain loads)
            #pragma unroll
            for (int i = 0; i < 4; ++i) {
                int rr = row0 + 4 * i;
                const float* src = h0 + (size_t)(b0 + rr) * 512;
                float4 v0 = *(const float4*)(src + c * 4);
                float4 v1 = *(const float4*)(src + 256 + c * 4);
                f16* e0 = hhi + rr * HS_LDA + c * 4;
                f16* e1 = e0 + 256;
                e0[0] = (f16)v0.x; e0[1] = (f16)v0.y; e0[2] = (f16)v0.z; e0[3] = (f16)v0.w;
                e1[0] = (f16)v1.x; e1[1] = (f16)v1.y; e1[2] = (f16)v1.z; e1[3] = (f16)v1.w;
            }
            __syncthreads();
            #pragma unroll
            for (int kc = 0; kc < 16; ++kc) {
                f16x8 a = *(const f16x8*)(arow + kc * 32);
                acc0 = __builtin_amdgcn_mfma_f32_16x16x32_f16(a, bf0[kc], acc0, 0, 0, 0);
                acc1 = __builtin_amdgcn_mfma_f32_16x16x32_f16(a, bf1[kc], acc1, 0, 0, 0);
            }
            __syncthreads();
        }

        // epilogue: h = tanh(Wh.h_hi + xt + bh); store tagged {hi,lo} via IC
        #pragma unroll
        for (int r = 0; r < 4; ++r) {
            size_t base = ((size_t)(b0 + rbase + r) * 1024 + tt) * 512;
            float h0v = fast_tanh(acc0[r] + unpack_sum(xtw0[r]) + bh0);
            float h1v = fast_tanh(acc1[r] + unpack_sum(xtw1[r]) + bh1);
            st_ic_u32(xsu + base + jg0, pack_h(h0v));
            st_ic_u32(xsu + base + jg1, pack_h(h1v));
        }
    }
}

// ---------------- merge: out = h_f + h_b ----------------
// Plain loads: dispatch-boundary L2 invalidate (proven by the proj->rnn xt
// path since R1) makes the IC-resident h words visible.
__global__ __launch_bounds__(256)
void merge_out(const u32x4* __restrict__ xsF, const u32x4* __restrict__ xsB,
               float* __restrict__ out)
{
    size_t i = (size_t)blockIdx.x * 256 + threadIdx.x;
    size_t stride = (size_t)gridDim.x * 256;
    for (; i < 8388608ULL; i += stride) {
        u32x4 a = xsF[i];
        u32x4 b = xsB[i];
        float4 o;
        o.x = unpack_sum(a.x) + unpack_sum(b.x);
        o.y = unpack_sum(a.y) + unpack_sum(b.y);
        o.z = unpack_sum(a.z) + unpack_sum(b.z);
        o.w = unpack_sum(a.w) + unpack_sum(b.w);
        *(float4*)(out + i * 4) = o;
    }
}

__global__ __launch_bounds__(256)
void copy_hidden(const float* __restrict__ hs, float* __restrict__ out)
{
    size_t i = (size_t)blockIdx.x * 256 + threadIdx.x;
    if (i < 32768) out[33554432ULL + i] = hs[i];
}

// ---------------- launch ----------------
extern "C" void kernel_launch(void* const* d_in, const int* in_sizes, int n_in,
                              void* d_out, int out_size, void* d_ws, size_t ws_size,
                              hipStream_t stream) {
    const float* x    = (const float*)d_in[0];
    const float* hs   = (const float*)d_in[1];
    const float* Wi_f = (const float*)d_in[2];
    const float* bi_f = (const float*)d_in[3];
    const float* Wh_f = (const float*)d_in[4];
    const float* bh_f = (const float*)d_in[5];
    const float* Wi_b = (const float*)d_in[6];
    const float* bi_b = (const float*)d_in[7];
    const float* Wh_b = (const float*)d_in[8];
    const float* bh_b = (const float*)d_in[9];

    float* out = (float*)d_out;
    char* ws = (char*)d_ws;

    unsigned* xsF = (unsigned*)out;             // forward history lives in d_out
    unsigned* xsB = (unsigned*)(ws + XSB_OFF);
    f16* w16      = (f16*)(ws + W16_OFF);

    cvt_w<<<1024, 256, 0, stream>>>(Wi_f, Wh_f, Wi_b, Wh_b, w16);
    proj<<<4096, 256, 0, stream>>>(x, w16, bi_f, bi_b, xsF, xsB);

    rnn_rec<<<32, 256, 0, stream>>>(hs, w16, bh_f, bh_b, xsF, xsB);

    merge_out<<<2048, 256, 0, stream>>>((const u32x4*)xsF, (const u32x4*)xsB, out);
    copy_hidden<<<128, 256, 0, stream>>>(hs, out);
}